// Round 6
// baseline (33652.820 us; speedup 1.0000x reference)
//
#include <hip/hip_runtime.h>
#include <hip/hip_bf16.h>
#include <math.h>

#define MINN 1e-7f

// Problem dims (fixed by setup_inputs)
#define BB 64
#define SS 128
#define NCOL 3840            // 768 (W_d) + 4*768 (gates)
#define NWG 240              // NCOL/16

typedef float f4 __attribute__((ext_vector_type(4)));

// Volatile (sc0|sc1) accessors: bypass non-coherent L1/L2, hit device coherence
// point (L3). Used for ALL cross-WG shared data -> no cache fences needed.
__device__ __forceinline__ f4 vload4(const float* p) { return *(const volatile f4*)p; }
__device__ __forceinline__ float vloadf(const float* p) { return *(const volatile float*)p; }
__device__ __forceinline__ void vstore(float* p, float v) { *(volatile float*)p = v; }

__device__ __forceinline__ float artanh_c(float x) {
  x = fminf(fmaxf(x, -1.0f + 1e-6f), 1.0f - 1e-6f);
  return atanhf(x);
}
__device__ __forceinline__ float tan_k_(float x, float sq) { return tanhf(sq * x) / sq; }
__device__ __forceinline__ float artan_k_(float x, float sq) { return artanh_c(sq * x) / sq; }

// Block reduction over 512 threads (8 waves).
template <int N>
__device__ __forceinline__ void block_reduce_sum8(float* v, float* red) {
#pragma unroll
  for (int m = 1; m < 64; m <<= 1) {
#pragma unroll
    for (int i = 0; i < N; ++i) v[i] += __shfl_xor(v[i], m, 64);
  }
  int wid = threadIdx.x >> 6;
  int lane = threadIdx.x & 63;
  if (lane == 0) {
#pragma unroll
    for (int i = 0; i < N; ++i) red[wid * N + i] = v[i];
  }
  __syncthreads();
#pragma unroll
  for (int i = 0; i < N; ++i) {
    float s = 0.f;
#pragma unroll
    for (int w = 0; w < 8; ++w) s += red[w * N + i];
    v[i] = s;
  }
  __syncthreads();
}

// Fence-free grid barrier: data moves via volatile(sc0|sc1) ops, so no L2
// writeback/invalidate is needed. Pure flag counting with relaxed atomics.
__device__ __forceinline__ void gbar(unsigned int* flags, unsigned int gen) {
  __syncthreads();  // per-thread vmcnt(0) before s_barrier drains our stores
  if (threadIdx.x == 0)
    __hip_atomic_store(&flags[blockIdx.x], gen, __ATOMIC_RELAXED, __HIP_MEMORY_SCOPE_AGENT);
  if (threadIdx.x < NWG) {
    while (__hip_atomic_load(&flags[threadIdx.x], __ATOMIC_RELAXED,
                             __HIP_MEMORY_SCOPE_AGENT) < gen) {
      __builtin_amdgcn_s_sleep(8);
    }
  }
  __syncthreads();
}

// Build combined weight matrix, chunked: CW[j][c][k] = weight(k, col=j*16+c)
__global__ __launch_bounds__(256) void k_build_cw(const float* __restrict__ W_all,
                                                  const float* __restrict__ W_d,
                                                  float* __restrict__ CW) {
  int j = blockIdx.x;
  float* dst = CW + (size_t)j * 12288;
  for (int idx = threadIdx.x; idx < 12288; idx += 256) {
    int c = idx / 768;
    int k = idx - c * 768;
    int col = j * 16 + c;
    float v;
    if (col < 768) {
      v = W_d[col * 768 + k];
    } else {
      int jm = col - 768;
      int g = jm / 768;
      int j2 = jm - g * 768;
      v = W_all[j2 * 3072 + g * 768 + k];
    }
    dst[idx] = v;
  }
}

__global__ __launch_bounds__(256) void k_xnorm(const float* __restrict__ X,
                                               float* __restrict__ XN) {
  __shared__ float red[4];
  int r = blockIdx.x;
  float s = 0.f;
#pragma unroll
  for (int p = 0; p < 3; ++p) {
    float v = X[(size_t)r * 768 + threadIdx.x + 256 * p];
    s += v * v;
  }
#pragma unroll
  for (int m = 1; m < 64; m <<= 1) s += __shfl_xor(s, m, 64);
  if ((threadIdx.x & 63) == 0) red[threadIdx.x >> 6] = s;
  __syncthreads();
  if (threadIdx.x == 0) XN[r] = fmaxf(sqrtf(red[0] + red[1] + red[2] + red[3]), MINN);
}

// C[i][m] = sum_k X[i][k] * U[m][k];  M=8192, N=3072, K=768. Output bf16.
__global__ __launch_bounds__(256) void k_gemm_xu(const float* __restrict__ X,
                                                 const float* __restrict__ U,
                                                 __hip_bfloat16* __restrict__ OUT) {
  __shared__ float As[64][17];
  __shared__ float Bs[64][17];
  int tid = threadIdx.x;
  int lr = tid >> 2;
  int lk = (tid & 3) * 4;
  int tm = tid & 15;
  int ti = tid >> 4;
  const float* xr = X + (size_t)(blockIdx.x * 64 + lr) * 768 + lk;
  const float* ur = U + (size_t)(blockIdx.y * 64 + lr) * 768 + lk;
  float acc[4][4];
#pragma unroll
  for (int a = 0; a < 4; ++a)
#pragma unroll
    for (int b = 0; b < 4; ++b) acc[a][b] = 0.f;

  for (int kt = 0; kt < 768; kt += 16) {
    float4 a = *(const float4*)(xr + kt);
    float4 b = *(const float4*)(ur + kt);
    As[lr][lk + 0] = a.x; As[lr][lk + 1] = a.y; As[lr][lk + 2] = a.z; As[lr][lk + 3] = a.w;
    Bs[lr][lk + 0] = b.x; Bs[lr][lk + 1] = b.y; Bs[lr][lk + 2] = b.z; Bs[lr][lk + 3] = b.w;
    __syncthreads();
#pragma unroll
    for (int k = 0; k < 16; ++k) {
      float av[4], bv[4];
#pragma unroll
      for (int q = 0; q < 4; ++q) {
        av[q] = As[ti * 4 + q][k];
        bv[q] = Bs[tm * 4 + q][k];
      }
#pragma unroll
      for (int rr = 0; rr < 4; ++rr)
#pragma unroll
        for (int c2 = 0; c2 < 4; ++c2) acc[rr][c2] += av[rr] * bv[c2];
    }
    __syncthreads();
  }
#pragma unroll
  for (int rr = 0; rr < 4; ++rr)
#pragma unroll
    for (int c2 = 0; c2 < 4; ++c2)
      OUT[(size_t)(blockIdx.x * 64 + ti * 4 + rr) * 3072 + blockIdx.y * 64 + tm * 4 + c2] =
          __float2bfloat16(acc[rr][c2]);
}

// Persistent scan: 240 WGs x 512 threads, fence-free flag barrier.
// Phase A (all WGs): 16 cols each, k split across thread halves, 8-load dbuf pipeline.
// Phase B (WGs 0..63): hyperbolic pointwise update; c/h state in registers.
__global__ __launch_bounds__(512, 1) void k_scan(
    const float* __restrict__ CW, float* __restrict__ ccT, float* __restrict__ hT,
    float* __restrict__ GOUT, const __hip_bfloat16* __restrict__ UG,
    const float* __restrict__ XN, const float* __restrict__ TS,
    const float* __restrict__ kptr, const float* __restrict__ h0,
    const float* __restrict__ c0, float* __restrict__ out, unsigned int* __restrict__ flags) {
  __shared__ float Wl[16 * 772];  // 49.4 KB weight chunk, [c][k] padded (+4) vs bank conflicts
  __shared__ f4 Pacc[512];        // 8 KB phase-A partial combine
  __shared__ float red[8 * 15];   // reductions
  int wg = blockIdx.x;
  int tid = threadIdx.x;

  // Stage this WG's weight chunk once: CW[j][c][k] -> Wl[c][772] (b128 rows).
  {
    const f4* s4 = (const f4*)(CW + (size_t)wg * 12288);
#pragma unroll
    for (int it = 0; it < 6; ++it) {
      int f = tid + 512 * it;
      int cc = f / 192;
      int kq = f - cc * 192;
      *(f4*)&Wl[cc * 772 + kq * 4] = s4[f];
    }
  }

  float kk = kptr[0];
  float sq = sqrtf(-kk);
  int r = wg;                 // row owned in phase B (wg < 64 only)
  bool full = tid < 256;      // second element (j1) valid
  int j0 = tid, j1 = 512 + tid;

  // Register-resident recurrent state for phase B owners.
  float cc0 = 0.f, cc1 = 0.f, h_0 = 0.f, h_1 = 0.f;
  if (wg < BB) {
    cc0 = c0[r * 768 + j0];
    h_0 = h0[r * 768 + j0];
    vstore(&ccT[j0 * 64 + r], cc0);
    vstore(&hT[j0 * 64 + r], h_0);
    if (full) {
      cc1 = c0[r * 768 + j1];
      h_1 = h0[r * 768 + j1];
      vstore(&ccT[j1 * 64 + r], cc1);
      vstore(&hT[j1 * 64 + r], h_1);
    }
  }
  unsigned int barn = 0;
  gbar(flags, ++barn);

  for (int t = 0; t < SS; ++t) {
    // ---------------- Phase A: recurrent GEMM (all 240 WGs) ----------------
    {
      const float* src = (wg < 48) ? ccT : hT;
      int c = tid & 15;
      int rg = (tid >> 4) & 15;
      int kh = tid >> 8;  // 0 or 1: k-half
      const float* sp = src + 4 * rg;  // + k*64 per hidden index k
      const int kb0 = kh * 384;        // this half's k-base
      const float* wrow = &Wl[c * 772];
      float a0 = 0.f, a1 = 0.f, a2 = 0.f, a3 = 0.f;
      f4 bufA[8], bufB[8];
#pragma unroll
      for (int i = 0; i < 8; ++i) bufA[i] = vload4(sp + (size_t)(kb0 + i) * 64);
      for (int kb = 0; kb < 48; kb += 2) {
#pragma unroll
        for (int i = 0; i < 8; ++i)
          bufB[i] = vload4(sp + (size_t)(kb0 + (kb + 1) * 8 + i) * 64);
#pragma unroll
        for (int iq = 0; iq < 2; ++iq) {
          f4 w = *(const f4*)(wrow + kb0 + kb * 8 + iq * 4);
#pragma unroll
          for (int j = 0; j < 4; ++j) {
            float wj = (j == 0) ? w.x : (j == 1) ? w.y : (j == 2) ? w.z : w.w;
            f4 s = bufA[iq * 4 + j];
            a0 += s.x * wj; a1 += s.y * wj; a2 += s.z * wj; a3 += s.w * wj;
          }
        }
        if (kb + 2 < 48) {
#pragma unroll
          for (int i = 0; i < 8; ++i)
            bufA[i] = vload4(sp + (size_t)(kb0 + (kb + 2) * 8 + i) * 64);
        }
#pragma unroll
        for (int iq = 0; iq < 2; ++iq) {
          f4 w = *(const f4*)(wrow + kb0 + (kb + 1) * 8 + iq * 4);
#pragma unroll
          for (int j = 0; j < 4; ++j) {
            float wj = (j == 0) ? w.x : (j == 1) ? w.y : (j == 2) ? w.z : w.w;
            f4 s = bufB[iq * 4 + j];
            a0 += s.x * wj; a1 += s.y * wj; a2 += s.z * wj; a3 += s.w * wj;
          }
        }
      }
      f4 pv;
      pv.x = a0; pv.y = a1; pv.z = a2; pv.w = a3;
      Pacc[tid] = pv;
      __syncthreads();
      if (tid < 256) {
        f4 p0 = Pacc[tid];
        f4 p1 = Pacc[tid + 256];
        int col = wg * 16 + (tid & 15);
        int rg2 = tid >> 4;
        vstore(&GOUT[(4 * rg2 + 0) * NCOL + col], p0.x + p1.x);
        vstore(&GOUT[(4 * rg2 + 1) * NCOL + col], p0.y + p1.y);
        vstore(&GOUT[(4 * rg2 + 2) * NCOL + col], p0.z + p1.z);
        vstore(&GOUT[(4 * rg2 + 3) * NCOL + col], p0.w + p1.w);
      }
    }
    gbar(flags, ++barn);

    // ---------------- Phase B: pointwise hyperbolic update (WGs 0..63) ------
    if (wg < BB) {
      const float* grow = GOUT + r * NCOL;
      int i = r * SS + t;
      const __hip_bfloat16* urow = UG + (size_t)i * 3072;

      float mv0, mv1, gh0[4], gh1[4], mx0[4], mx1[4];
      mv0 = vloadf(grow + j0);
      mv1 = full ? vloadf(grow + j1) : 0.f;
#pragma unroll
      for (int g = 0; g < 4; ++g) {
        gh0[g] = vloadf(grow + 768 + g * 768 + j0);
        gh1[g] = full ? vloadf(grow + 768 + g * 768 + j1) : 0.f;
        mx0[g] = __bfloat162float(urow[g * 768 + j0]);
        mx1[g] = full ? __bfloat162float(urow[g * 768 + j1]) : 0.f;
      }

      // batch1: {c2, h2, mvn2, |gh_g|^2 x4, gh_g.mx_g x4, |mx_g|^2 x4}
      float sv[15];
#pragma unroll
      for (int q = 0; q < 15; ++q) sv[q] = 0.f;
      sv[0] = cc0 * cc0 + cc1 * cc1;
      sv[1] = h_0 * h_0 + h_1 * h_1;
      sv[2] = mv0 * mv0 + mv1 * mv1;
#pragma unroll
      for (int g = 0; g < 4; ++g) {
        sv[3 + g] = gh0[g] * gh0[g] + gh1[g] * gh1[g];
        sv[7 + g] = gh0[g] * mx0[g] + gh1[g] * mx1[g];
        sv[11 + g] = mx0[g] * mx0[g] + mx1[g] * mx1[g];
      }
      block_reduce_sum8<15>(sv, red);
      float c2 = sv[0], h2 = sv[1], mvn2 = sv[2];
      float xn_c = fmaxf(sqrtf(c2), MINN);
      float xn_h = fmaxf(sqrtf(h2), MINN);
      float mxn_d = fmaxf(sqrtf(mvn2), MINN);

      // W_d path
      float r_d = (mxn_d / xn_c) * artan_k_(xn_c, sq);
      float twd = tan_k_(r_d, sq);
      float wdsc = twd / mxn_d;
      float yn_d = fmaxf(fabsf(twd), MINN);
      float lsc = (artan_k_(yn_d, sq) / yn_d) * wdsc;
      float th0 = tanhf(lsc * mv0);
      float th1 = tanhf(lsc * mv1);

      // gates
      float uxn = XN[i];
      float ak_h = artan_k_(xn_h, sq);
      float ak_u = artan_k_(uxn, sq);
      float cAg[4], cBg[4], pscg[4];
#pragma unroll
      for (int g = 0; g < 4; ++g) {
        float ghn = fmaxf(sqrtf(sv[3 + g]), MINN);
        float tg = tan_k_((ghn / xn_h) * ak_h, sq);
        float wsc = tg / ghn;
        float w2 = tg * tg;
        float umxn = fmaxf(sqrtf(sv[11 + g]), MINN);
        float us = tan_k_((umxn / uxn) * ak_u, sq) / umxn;
        float u2 = us * us * sv[11 + g];
        float xy = wsc * us * sv[7 + g];
        float den = fmaxf(1.f - 2.f * kk * xy + kk * kk * w2 * u2, MINN);
        float a = (1.f - 2.f * kk * xy - kk * u2) / den;
        float b = (1.f + kk * w2) / den;
        float y2s = fmaxf(a * a * w2 + 2.f * a * b * xy + b * b * u2, 0.f);
        float yn = fmaxf(sqrtf(y2s), MINN);
        pscg[g] = artan_k_(yn, sq) / yn;
        cAg[g] = a * wsc;
        cBg[g] = b * us;
      }
      float gate0[4], gate1[4];
#pragma unroll
      for (int g = 0; g < 4; ++g) {
        gate0[g] = 1.f / (1.f + expf(-pscg[g] * (cAg[g] * gh0[g] + cBg[g] * mx0[g])));
        gate1[g] = 1.f / (1.f + expf(-pscg[g] * (cAg[g] * gh1[g] + cBg[g] * mx1[g])));
      }

      // batch2: {|th|^2, th.cc}
      float s2v[2];
      s2v[0] = th0 * th0 + th1 * th1;
      s2v[1] = th0 * cc0 + th1 * cc1;
      block_reduce_sum8<2>(s2v, red);
      float un = fmaxf(sqrtf(s2v[0]), MINN);
      float esc = tan_k_(un, sq) / un;
      float cs1_0 = esc * th0, cs1_1 = esc * th1;
      float d1 = esc * s2v[1];
      float s1sq = esc * esc * s2v[0];

      // c_s2 = s2s * cs1
      float tv = TS[r * SS + t];
      float xnt = fmaxf(sqrtf(768.f * tv * tv), MINN);
      float wxn_t = fmaxf(fabsf(tv) * sqrtf(s1sq), MINN);
      float s2s = tan_k_((wxn_t / xnt) * artan_k_(xnt, sq), sq) / wxn_t * tv;
      float s2sq = s2s * s2s * s1sq;

      // c_l = mobius_add(-cs1, cc)
      float den_l = fmaxf(1.f + 2.f * kk * d1 + kk * kk * s1sq * c2, MINN);
      float al = (1.f + 2.f * kk * d1 - kk * c2) / den_l;
      float bl = (1.f + kk * s1sq) / den_l;
      float pcl = -al, qcl = bl;

      // c_adj = mobius_add(c_l, c_s2)
      float xy2 = s2s * (pcl * s1sq + qcl * d1);
      float x2b = fmaxf(pcl * pcl * s1sq + 2.f * pcl * qcl * d1 + qcl * qcl * c2, 0.f);
      float y2b = s2sq;
      float den2 = fmaxf(1.f - 2.f * kk * xy2 + kk * kk * x2b * y2b, MINN);
      float a2 = (1.f - 2.f * kk * xy2 - kk * y2b) / den2;
      float b2 = (1.f + kk * x2b) / den2;
      float g1c = a2 * pcl + b2 * s2s;
      float g2c = a2 * qcl;
      float cadj0 = g1c * cs1_0 + g2c * cc0;
      float cadj1 = g1c * cs1_1 + g2c * cc1;
      float adjsq = fmaxf(g1c * g1c * s1sq + 2.f * g1c * g2c * d1 + g2c * g2c * c2, 0.f);

      // new_c = madd(pmul(i,c_tmp), pmul(f,c_adj))
      float wxi0 = gate0[1] * gate0[3], wxi1 = gate1[1] * gate1[3];
      float wxf0 = gate0[0] * cadj0, wxf1 = gate1[0] * cadj1;
      float s3v[4];
      s3v[0] = gate0[3] * gate0[3];
      s3v[1] = wxi0 * wxi0;
      s3v[2] = wxf0 * wxf0;
      s3v[3] = wxi0 * wxf0;
      if (full) {
        s3v[0] += gate1[3] * gate1[3];
        s3v[1] += wxi1 * wxi1;
        s3v[2] += wxf1 * wxf1;
        s3v[3] += wxi1 * wxf1;
      }
      block_reduce_sum8<4>(s3v, red);
      float xnct = fmaxf(sqrtf(s3v[0]), MINN);
      float wxni = fmaxf(sqrtf(s3v[1]), MINN);
      float psi = tan_k_((wxni / xnct) * artan_k_(xnct, sq), sq) / wxni;
      float pi2 = psi * psi * s3v[1];
      float xnadj = fmaxf(sqrtf(adjsq), MINN);
      float wxnf = fmaxf(sqrtf(s3v[2]), MINN);
      float psf = tan_k_((wxnf / xnadj) * artan_k_(xnadj, sq), sq) / wxnf;
      float pf2 = psf * psf * s3v[2];
      float xyp = psi * psf * s3v[3];
      float den3 = fmaxf(1.f - 2.f * kk * xyp + kk * kk * pi2 * pf2, MINN);
      float a3 = (1.f - 2.f * kk * xyp - kk * pf2) / den3;
      float b3 = (1.f + kk * pi2) / den3;
      float nc0 = a3 * psi * wxi0 + b3 * psf * wxf0;
      float nc1 = a3 * psi * wxi1 + b3 * psf * wxf1;
      float tc0 = tanhf(nc0), tc1 = tanhf(nc1);
      float s4v[1];
      s4v[0] = tc0 * tc0 + (full ? tc1 * tc1 : 0.f);
      block_reduce_sum8<1>(s4v, red);
      float unh = fmaxf(sqrtf(s4v[0]), MINN);
      float ehs = tan_k_(unh, sq) / unh;
      float Esq = ehs * ehs * s4v[0];
      float En = fmaxf(sqrtf(Esq), MINN);
      float wxo0 = gate0[2] * (ehs * tc0);
      float wxo1 = gate1[2] * (ehs * tc1);
      float s5v[1];
      s5v[0] = wxo0 * wxo0 + (full ? wxo1 * wxo1 : 0.f);
      block_reduce_sum8<1>(s5v, red);
      float wxno = fmaxf(sqrtf(s5v[0]), MINN);
      float pso = tan_k_((wxno / En) * artan_k_(En, sq), sq) / wxno;

      size_t BSHc = (size_t)BB * SS * 768;
      out[((size_t)r * SS + t) * 768 + j0] = gate0[2];
      float nh0 = pso * wxo0;
      cc0 = nc0; h_0 = nh0;
      vstore(&ccT[j0 * 64 + r], nc0);
      vstore(&hT[j0 * 64 + r], nh0);
      if (t == SS - 1) {
        out[BSHc + (size_t)r * 768 + j0] = nh0;
        out[BSHc + (size_t)BB * 768 + (size_t)r * 768 + j0] = nc0;
      }
      if (full) {
        out[((size_t)r * SS + t) * 768 + j1] = gate1[2];
        float nh1 = pso * wxo1;
        cc1 = nc1; h_1 = nh1;
        vstore(&ccT[j1 * 64 + r], nc1);
        vstore(&hT[j1 * 64 + r], nh1);
        if (t == SS - 1) {
          out[BSHc + (size_t)r * 768 + j1] = nh1;
          out[BSHc + (size_t)BB * 768 + (size_t)r * 768 + j1] = nc1;
        }
      }
    }
    if (t < SS - 1) {
      gbar(flags, ++barn);
    }
  }
}

extern "C" void kernel_launch(void* const* d_in, const int* in_sizes, int n_in,
                              void* d_out, int out_size, void* d_ws, size_t ws_size,
                              hipStream_t stream) {
  const float* inputs = (const float*)d_in[0];
  const float* ts = (const float*)d_in[1];
  const float* h0 = (const float*)d_in[2];
  const float* c0 = (const float*)d_in[3];
  const float* W_all = (const float*)d_in[4];
  const float* U_all = (const float*)d_in[5];
  const float* W_d = (const float*)d_in[6];
  const float* kptr = (const float*)d_in[7];
  float* ws = (float*)d_ws;
  float* out = (float*)d_out;

  size_t oBAR = 0;                               // 256 uints (1 KB) of flags
  size_t oCW = 256;
  size_t oCCT = oCW + (size_t)NWG * 12288;       // CW: 2,949,120 floats
  size_t oHT = oCCT + 49152;
  size_t oGOUT = oHT + 49152;
  size_t oXN = oGOUT + (size_t)BB * NCOL;
  size_t oUG = oXN + 8192;

  unsigned int* flags = (unsigned int*)(ws + oBAR);
  float* cw = ws + oCW;
  float* cct = ws + oCCT;
  float* ht = ws + oHT;
  float* gout = ws + oGOUT;
  float* xn = ws + oXN;
  __hip_bfloat16* ug = (__hip_bfloat16*)(ws + oUG);

  hipMemsetAsync(flags, 0, 1024, stream);
  k_build_cw<<<NWG, 256, 0, stream>>>(W_all, W_d, cw);
  k_gemm_xu<<<dim3(128, 48), 256, 0, stream>>>(inputs, U_all, ug);
  k_xnorm<<<BB * SS, 256, 0, stream>>>(inputs, xn);

  void* args[] = {(void*)&cw, (void*)&cct, (void*)&ht,   (void*)&gout,
                  (void*)&ug, (void*)&xn,  (void*)&ts,   (void*)&kptr,
                  (void*)&h0, (void*)&c0,  (void*)&out,  (void*)&flags};
  hipLaunchCooperativeKernel((void*)k_scan, dim3(NWG), dim3(512), args, 0, stream);
}

// Round 7
// 5687.004 us; speedup vs baseline: 5.9175x; 5.9175x over previous
//
#include <hip/hip_runtime.h>
#include <hip/hip_bf16.h>
#include <math.h>

#define MINN 1e-7f

// Problem dims (fixed by setup_inputs)
#define BB 64
#define SS 128
#define NCOL 3840            // 768 (W_d) + 4*768 (gates)
#define NCHUNK 480           // 8 cols per chunk

typedef float f4 __attribute__((ext_vector_type(4)));

__device__ __forceinline__ float artanh_c(float x) {
  x = fminf(fmaxf(x, -1.0f + 1e-6f), 1.0f - 1e-6f);
  return atanhf(x);
}
__device__ __forceinline__ float tan_k_(float x, float sq) { return tanhf(sq * x) / sq; }
__device__ __forceinline__ float artan_k_(float x, float sq) { return artanh_c(sq * x) / sq; }

// Block reduction over 256 threads (4 waves).
template <int N>
__device__ __forceinline__ void block_reduce_sum(float* v, float* red) {
#pragma unroll
  for (int m = 1; m < 64; m <<= 1) {
#pragma unroll
    for (int i = 0; i < N; ++i) v[i] += __shfl_xor(v[i], m, 64);
  }
  int wid = threadIdx.x >> 6;
  int lane = threadIdx.x & 63;
  if (lane == 0) {
#pragma unroll
    for (int i = 0; i < N; ++i) red[wid * N + i] = v[i];
  }
  __syncthreads();
#pragma unroll
  for (int i = 0; i < N; ++i) v[i] = red[i] + red[N + i] + red[2 * N + i] + red[3 * N + i];
  __syncthreads();
}

// Build combined weight matrix, chunk-major: CW[j][c][k] = weight(k, col=j*8+c)
__global__ __launch_bounds__(256) void k_build_cw(const float* __restrict__ W_all,
                                                  const float* __restrict__ W_d,
                                                  float* __restrict__ CW) {
  int j = blockIdx.x;
  float* dst = CW + (size_t)j * 6144;
  for (int idx = threadIdx.x; idx < 6144; idx += 256) {
    int c = idx / 768;
    int k = idx - c * 768;
    int col = j * 8 + c;
    float v;
    if (col < 768) {
      v = W_d[col * 768 + k];
    } else {
      int jm = col - 768;
      int g = jm / 768;
      int j2 = jm - g * 768;
      v = W_all[j2 * 3072 + g * 768 + k];
    }
    dst[idx] = v;
  }
}

__global__ __launch_bounds__(256) void k_init_state(const float* __restrict__ h0,
                                                    const float* __restrict__ c0,
                                                    float* __restrict__ ccR, float* __restrict__ hR,
                                                    float* __restrict__ ccT, float* __restrict__ hT) {
  int r = blockIdx.x;
#pragma unroll
  for (int p = 0; p < 3; ++p) {
    int j = threadIdx.x + 256 * p;
    float cv = c0[r * 768 + j];
    float hv = h0[r * 768 + j];
    ccR[r * 768 + j] = cv;
    hR[r * 768 + j] = hv;
    ccT[j * 64 + r] = cv;
    hT[j * 64 + r] = hv;
  }
}

__global__ __launch_bounds__(256) void k_xnorm(const float* __restrict__ X,
                                               float* __restrict__ XN) {
  __shared__ float red[4];
  int r = blockIdx.x;
  float s = 0.f;
#pragma unroll
  for (int p = 0; p < 3; ++p) {
    float v = X[(size_t)r * 768 + threadIdx.x + 256 * p];
    s += v * v;
  }
#pragma unroll
  for (int m = 1; m < 64; m <<= 1) s += __shfl_xor(s, m, 64);
  if ((threadIdx.x & 63) == 0) red[threadIdx.x >> 6] = s;
  __syncthreads();
  if (threadIdx.x == 0) XN[r] = fmaxf(sqrtf(red[0] + red[1] + red[2] + red[3]), MINN);
}

// C[i][m] = sum_k X[i][k] * U[m][k];  M=8192, N=3072, K=768. Output bf16.
__global__ __launch_bounds__(256) void k_gemm_xu(const float* __restrict__ X,
                                                 const float* __restrict__ U,
                                                 __hip_bfloat16* __restrict__ OUT) {
  __shared__ float As[64][17];
  __shared__ float Bs[64][17];
  int tid = threadIdx.x;
  int lr = tid >> 2;
  int lk = (tid & 3) * 4;
  int tm = tid & 15;
  int ti = tid >> 4;
  const float* xr = X + (size_t)(blockIdx.x * 64 + lr) * 768 + lk;
  const float* ur = U + (size_t)(blockIdx.y * 64 + lr) * 768 + lk;
  float acc[4][4];
#pragma unroll
  for (int a = 0; a < 4; ++a)
#pragma unroll
    for (int b = 0; b < 4; ++b) acc[a][b] = 0.f;

  for (int kt = 0; kt < 768; kt += 16) {
    float4 a = *(const float4*)(xr + kt);
    float4 b = *(const float4*)(ur + kt);
    As[lr][lk + 0] = a.x; As[lr][lk + 1] = a.y; As[lr][lk + 2] = a.z; As[lr][lk + 3] = a.w;
    Bs[lr][lk + 0] = b.x; Bs[lr][lk + 1] = b.y; Bs[lr][lk + 2] = b.z; Bs[lr][lk + 3] = b.w;
    __syncthreads();
#pragma unroll
    for (int k = 0; k < 16; ++k) {
      float av[4], bv[4];
#pragma unroll
      for (int q = 0; q < 4; ++q) {
        av[q] = As[ti * 4 + q][k];
        bv[q] = Bs[tm * 4 + q][k];
      }
#pragma unroll
      for (int rr = 0; rr < 4; ++rr)
#pragma unroll
        for (int c2 = 0; c2 < 4; ++c2) acc[rr][c2] += av[rr] * bv[c2];
    }
    __syncthreads();
  }
#pragma unroll
  for (int rr = 0; rr < 4; ++rr)
#pragma unroll
    for (int c2 = 0; c2 < 4; ++c2)
      OUT[(size_t)(blockIdx.x * 64 + ti * 4 + rr) * 3072 + blockIdx.y * 64 + tm * 4 + c2] =
          __float2bfloat16(acc[rr][c2]);
}

// Per-step GEMM: GOUT[row][col] = sum_k state[k][row] * W[k][col].
// 480 WGs x 512 thr (2 WG/CU): 8 cols/WG, 4-way k-split, f4 dbuf pipeline.
__global__ __launch_bounds__(512) void k_step_gemm(const float* __restrict__ CW,
                                                   const float* __restrict__ ccT,
                                                   const float* __restrict__ hT,
                                                   float* __restrict__ GOUT) {
  __shared__ float Wl[8 * 772];  // 24.7 KB, [c][k] padded rows: b128-conflict-free
  __shared__ f4 Pacc[512];       // 8 KB partial combine
  int j = blockIdx.x;
  int tid = threadIdx.x;

  // Stage weights: 1536 f4 over 512 threads x 3.
  {
    const f4* s4 = (const f4*)(CW + (size_t)j * 6144);
#pragma unroll
    for (int it = 0; it < 3; ++it) {
      int f = tid + 512 * it;
      int cc = f / 192;        // col within chunk
      int kq = f - cc * 192;   // f4-group within col
      *(f4*)&Wl[cc * 772 + kq * 4] = s4[f];
    }
  }
  __syncthreads();

  const float* src = (j < 96) ? ccT : hT;
  int c = tid & 7;
  int rg = (tid >> 3) & 15;  // row-quad 0..15
  int kh = tid >> 7;         // k-quarter 0..3
  const float* sp = src + 4 * rg;   // + k*64 per hidden index k
  const int kb0 = kh * 192;
  const float* wrow = &Wl[c * 772];
  float a0 = 0.f, a1 = 0.f, a2 = 0.f, a3 = 0.f;
  f4 bufA[8], bufB[8];
#pragma unroll
  for (int i = 0; i < 8; ++i) bufA[i] = *(const f4*)(sp + (size_t)(kb0 + i) * 64);
  for (int kb = 0; kb < 24; kb += 2) {
#pragma unroll
    for (int i = 0; i < 8; ++i)
      bufB[i] = *(const f4*)(sp + (size_t)(kb0 + (kb + 1) * 8 + i) * 64);
#pragma unroll
    for (int iq = 0; iq < 2; ++iq) {
      f4 w = *(const f4*)(wrow + kb0 + kb * 8 + iq * 4);
#pragma unroll
      for (int jj = 0; jj < 4; ++jj) {
        float wj = (jj == 0) ? w.x : (jj == 1) ? w.y : (jj == 2) ? w.z : w.w;
        f4 s = bufA[iq * 4 + jj];
        a0 += s.x * wj; a1 += s.y * wj; a2 += s.z * wj; a3 += s.w * wj;
      }
    }
    if (kb + 2 < 24) {
#pragma unroll
      for (int i = 0; i < 8; ++i)
        bufA[i] = *(const f4*)(sp + (size_t)(kb0 + (kb + 2) * 8 + i) * 64);
    }
#pragma unroll
    for (int iq = 0; iq < 2; ++iq) {
      f4 w = *(const f4*)(wrow + kb0 + (kb + 1) * 8 + iq * 4);
#pragma unroll
      for (int jj = 0; jj < 4; ++jj) {
        float wj = (jj == 0) ? w.x : (jj == 1) ? w.y : (jj == 2) ? w.z : w.w;
        f4 s = bufB[iq * 4 + jj];
        a0 += s.x * wj; a1 += s.y * wj; a2 += s.z * wj; a3 += s.w * wj;
      }
    }
  }
  f4 pv;
  pv.x = a0; pv.y = a1; pv.z = a2; pv.w = a3;
  Pacc[tid] = pv;
  __syncthreads();
  if (tid < 128) {
    f4 p0 = Pacc[tid];
    f4 p1 = Pacc[tid + 128];
    f4 p2 = Pacc[tid + 256];
    f4 p3 = Pacc[tid + 384];
    int c2 = tid & 7;
    int rg2 = tid >> 3;
    int col = j * 8 + c2;
    GOUT[(4 * rg2 + 0) * NCOL + col] = p0.x + p1.x + p2.x + p3.x;
    GOUT[(4 * rg2 + 1) * NCOL + col] = p0.y + p1.y + p2.y + p3.y;
    GOUT[(4 * rg2 + 2) * NCOL + col] = p0.z + p1.z + p2.z + p3.z;
    GOUT[(4 * rg2 + 3) * NCOL + col] = p0.w + p1.w + p2.w + p3.w;
  }
}

// Per-step pointwise hyperbolic math; one WG per batch row (r1-proven).
__global__ __launch_bounds__(256) void k_step_pw(
    const float* __restrict__ GOUT, const __hip_bfloat16* __restrict__ UG,
    const float* __restrict__ XN, const float* __restrict__ TS,
    const float* __restrict__ kptr, float* __restrict__ ccR, float* __restrict__ hR,
    float* __restrict__ ccT, float* __restrict__ hT, float* __restrict__ out, int t) {
  __shared__ float red[64];
  int r = blockIdx.x;
  int tid = threadIdx.x;
  float kk = kptr[0];
  float sq = sqrtf(-kk);
  const float* grow = GOUT + r * NCOL;
  int i = r * SS + t;
  const __hip_bfloat16* urow = UG + (size_t)i * 3072;

  float cc[3], h[3], mv[3], gh[4][3], mx[4][3];
#pragma unroll
  for (int p = 0; p < 3; ++p) {
    int j = tid + 256 * p;
    cc[p] = ccR[r * 768 + j];
    h[p] = hR[r * 768 + j];
    mv[p] = grow[j];
#pragma unroll
    for (int g = 0; g < 4; ++g) {
      gh[g][p] = grow[768 + g * 768 + j];
      mx[g][p] = __bfloat162float(urow[g * 768 + j]);
    }
  }

  float sv[15];
#pragma unroll
  for (int q = 0; q < 15; ++q) sv[q] = 0.f;
#pragma unroll
  for (int p = 0; p < 3; ++p) {
    sv[0] += cc[p] * cc[p];
    sv[1] += h[p] * h[p];
    sv[2] += mv[p] * mv[p];
#pragma unroll
    for (int g = 0; g < 4; ++g) {
      sv[3 + g] += gh[g][p] * gh[g][p];
      sv[7 + g] += gh[g][p] * mx[g][p];
      sv[11 + g] += mx[g][p] * mx[g][p];
    }
  }
  block_reduce_sum<15>(sv, red);
  float c2 = sv[0], h2 = sv[1], mvn2 = sv[2];
  float xn_c = fmaxf(sqrtf(c2), MINN);
  float xn_h = fmaxf(sqrtf(h2), MINN);
  float mxn_d = fmaxf(sqrtf(mvn2), MINN);

  float r_d = (mxn_d / xn_c) * artan_k_(xn_c, sq);
  float twd = tan_k_(r_d, sq);
  float wdsc = twd / mxn_d;
  float yn_d = fmaxf(fabsf(twd), MINN);
  float lsc = (artan_k_(yn_d, sq) / yn_d) * wdsc;
  float th[3];
#pragma unroll
  for (int p = 0; p < 3; ++p) th[p] = tanhf(lsc * mv[p]);

  float uxn = XN[i];
  float ak_h = artan_k_(xn_h, sq);
  float ak_u = artan_k_(uxn, sq);
  float cAg[4], cBg[4], pscg[4];
#pragma unroll
  for (int g = 0; g < 4; ++g) {
    float ghn = fmaxf(sqrtf(sv[3 + g]), MINN);
    float tg = tan_k_((ghn / xn_h) * ak_h, sq);
    float wsc = tg / ghn;
    float w2 = tg * tg;
    float umxn = fmaxf(sqrtf(sv[11 + g]), MINN);
    float us = tan_k_((umxn / uxn) * ak_u, sq) / umxn;
    float u2 = us * us * sv[11 + g];
    float xy = wsc * us * sv[7 + g];
    float den = fmaxf(1.f - 2.f * kk * xy + kk * kk * w2 * u2, MINN);
    float a = (1.f - 2.f * kk * xy - kk * u2) / den;
    float b = (1.f + kk * w2) / den;
    float y2s = fmaxf(a * a * w2 + 2.f * a * b * xy + b * b * u2, 0.f);
    float yn = fmaxf(sqrtf(y2s), MINN);
    pscg[g] = artan_k_(yn, sq) / yn;
    cAg[g] = a * wsc;
    cBg[g] = b * us;
  }
  float gate[4][3];
#pragma unroll
  for (int g = 0; g < 4; ++g)
#pragma unroll
    for (int p = 0; p < 3; ++p)
      gate[g][p] = 1.f / (1.f + expf(-pscg[g] * (cAg[g] * gh[g][p] + cBg[g] * mx[g][p])));

  float s2v[2] = {0.f, 0.f};
#pragma unroll
  for (int p = 0; p < 3; ++p) {
    s2v[0] += th[p] * th[p];
    s2v[1] += th[p] * cc[p];
  }
  block_reduce_sum<2>(s2v, red);
  float un = fmaxf(sqrtf(s2v[0]), MINN);
  float esc = tan_k_(un, sq) / un;
  float cs1[3];
#pragma unroll
  for (int p = 0; p < 3; ++p) cs1[p] = esc * th[p];
  float d1 = esc * s2v[1];
  float s1sq = esc * esc * s2v[0];

  float tv = TS[r * SS + t];
  float xnt = fmaxf(sqrtf(768.f * tv * tv), MINN);
  float wxn_t = fmaxf(fabsf(tv) * sqrtf(s1sq), MINN);
  float s2s = tan_k_((wxn_t / xnt) * artan_k_(xnt, sq), sq) / wxn_t * tv;
  float s2sq = s2s * s2s * s1sq;

  float den_l = fmaxf(1.f + 2.f * kk * d1 + kk * kk * s1sq * c2, MINN);
  float al = (1.f + 2.f * kk * d1 - kk * c2) / den_l;
  float bl = (1.f + kk * s1sq) / den_l;
  float pcl = -al, qcl = bl;

  float xy2 = s2s * (pcl * s1sq + qcl * d1);
  float x2b = fmaxf(pcl * pcl * s1sq + 2.f * pcl * qcl * d1 + qcl * qcl * c2, 0.f);
  float y2b = s2sq;
  float den2 = fmaxf(1.f - 2.f * kk * xy2 + kk * kk * x2b * y2b, MINN);
  float a2 = (1.f - 2.f * kk * xy2 - kk * y2b) / den2;
  float b2 = (1.f + kk * x2b) / den2;
  float g1c = a2 * pcl + b2 * s2s;
  float g2c = a2 * qcl;
  float cadj[3];
#pragma unroll
  for (int p = 0; p < 3; ++p) cadj[p] = g1c * cs1[p] + g2c * cc[p];
  float adjsq = fmaxf(g1c * g1c * s1sq + 2.f * g1c * g2c * d1 + g2c * g2c * c2, 0.f);

  float wxi[3], wxf[3];
#pragma unroll
  for (int p = 0; p < 3; ++p) {
    wxi[p] = gate[1][p] * gate[3][p];
    wxf[p] = gate[0][p] * cadj[p];
  }
  float s3v[4] = {0.f, 0.f, 0.f, 0.f};
#pragma unroll
  for (int p = 0; p < 3; ++p) {
    s3v[0] += gate[3][p] * gate[3][p];
    s3v[1] += wxi[p] * wxi[p];
    s3v[2] += wxf[p] * wxf[p];
    s3v[3] += wxi[p] * wxf[p];
  }
  block_reduce_sum<4>(s3v, red);
  float xnct = fmaxf(sqrtf(s3v[0]), MINN);
  float wxni = fmaxf(sqrtf(s3v[1]), MINN);
  float psi = tan_k_((wxni / xnct) * artan_k_(xnct, sq), sq) / wxni;
  float pi2 = psi * psi * s3v[1];
  float xnadj = fmaxf(sqrtf(adjsq), MINN);
  float wxnf = fmaxf(sqrtf(s3v[2]), MINN);
  float psf = tan_k_((wxnf / xnadj) * artan_k_(xnadj, sq), sq) / wxnf;
  float pf2 = psf * psf * s3v[2];
  float xyp = psi * psf * s3v[3];
  float den3 = fmaxf(1.f - 2.f * kk * xyp + kk * kk * pi2 * pf2, MINN);
  float a3 = (1.f - 2.f * kk * xyp - kk * pf2) / den3;
  float b3 = (1.f + kk * pi2) / den3;
  float nc[3], tc[3];
#pragma unroll
  for (int p = 0; p < 3; ++p) {
    nc[p] = a3 * psi * wxi[p] + b3 * psf * wxf[p];
    tc[p] = tanhf(nc[p]);
  }
  float s4v[1] = {0.f};
#pragma unroll
  for (int p = 0; p < 3; ++p) s4v[0] += tc[p] * tc[p];
  block_reduce_sum<1>(s4v, red);
  float unh = fmaxf(sqrtf(s4v[0]), MINN);
  float ehs = tan_k_(unh, sq) / unh;
  float Esq = ehs * ehs * s4v[0];
  float En = fmaxf(sqrtf(Esq), MINN);
  float wxo[3];
#pragma unroll
  for (int p = 0; p < 3; ++p) wxo[p] = gate[2][p] * (ehs * tc[p]);
  float s5v[1] = {0.f};
#pragma unroll
  for (int p = 0; p < 3; ++p) s5v[0] += wxo[p] * wxo[p];
  block_reduce_sum<1>(s5v, red);
  float wxno = fmaxf(sqrtf(s5v[0]), MINN);
  float pso = tan_k_((wxno / En) * artan_k_(En, sq), sq) / wxno;

  size_t BSHc = (size_t)BB * SS * 768;
#pragma unroll
  for (int p = 0; p < 3; ++p) {
    int j = tid + 256 * p;
    out[((size_t)r * SS + t) * 768 + j] = gate[2][p];  // output = o gate
    float ncv = nc[p];
    float nhv = pso * wxo[p];
    ccR[r * 768 + j] = ncv;
    ccT[j * 64 + r] = ncv;
    hR[r * 768 + j] = nhv;
    hT[j * 64 + r] = nhv;
    if (t == SS - 1) {
      out[BSHc + (size_t)r * 768 + j] = nhv;                    // h_last
      out[BSHc + (size_t)BB * 768 + (size_t)r * 768 + j] = ncv; // c_last
    }
  }
}

extern "C" void kernel_launch(void* const* d_in, const int* in_sizes, int n_in,
                              void* d_out, int out_size, void* d_ws, size_t ws_size,
                              hipStream_t stream) {
  const float* inputs = (const float*)d_in[0];
  const float* ts = (const float*)d_in[1];
  const float* h0 = (const float*)d_in[2];
  const float* c0 = (const float*)d_in[3];
  const float* W_all = (const float*)d_in[4];
  const float* U_all = (const float*)d_in[5];
  const float* W_d = (const float*)d_in[6];
  const float* kptr = (const float*)d_in[7];
  float* ws = (float*)d_ws;
  float* out = (float*)d_out;

  size_t oCW = 0;
  size_t oCCT = oCW + (size_t)NCHUNK * 6144;  // 2,949,120 floats
  size_t oHT = oCCT + 49152;
  size_t oCCR = oHT + 49152;
  size_t oHR = oCCR + 49152;
  size_t oGOUT = oHR + 49152;
  size_t oXN = oGOUT + (size_t)BB * NCOL;
  size_t oUG = oXN + 8192;

  float* cw = ws + oCW;
  float* cct = ws + oCCT;
  float* ht = ws + oHT;
  float* ccr = ws + oCCR;
  float* hr = ws + oHR;
  float* gout = ws + oGOUT;
  float* xn = ws + oXN;
  __hip_bfloat16* ug = (__hip_bfloat16*)(ws + oUG);

  k_build_cw<<<NCHUNK, 256, 0, stream>>>(W_all, W_d, cw);
  k_init_state<<<BB, 256, 0, stream>>>(h0, c0, ccr, hr, cct, ht);
  k_gemm_xu<<<dim3(128, 48), 256, 0, stream>>>(inputs, U_all, ug);
  k_xnorm<<<BB * SS, 256, 0, stream>>>(inputs, xn);

  for (int t = 0; t < SS; ++t) {
    k_step_gemm<<<NCHUNK, 512, 0, stream>>>(cw, cct, ht, gout);
    k_step_pw<<<BB, 256, 0, stream>>>(gout, ug, xn, ts, kptr, ccr, hr, cct, ht, out, t);
  }
}

// Round 8
// 5551.071 us; speedup vs baseline: 6.0624x; 1.0245x over previous
//
#include <hip/hip_runtime.h>
#include <hip/hip_bf16.h>
#include <math.h>

#define MINN 1e-7f

// Problem dims (fixed by setup_inputs)
#define BB 64
#define SS 128
#define NCOL 3840            // 768 (W_d) + 4*768 (gates)
#define NCHUNK 480           // 8 cols per chunk

typedef float f4 __attribute__((ext_vector_type(4)));
typedef short bf16x8 __attribute__((ext_vector_type(8)));
typedef float f32x4 __attribute__((ext_vector_type(4)));

__device__ __forceinline__ float artanh_c(float x) {
  x = fminf(fmaxf(x, -1.0f + 1e-6f), 1.0f - 1e-6f);
  return atanhf(x);
}
__device__ __forceinline__ float tan_k_(float x, float sq) { return tanhf(sq * x) / sq; }
__device__ __forceinline__ float artan_k_(float x, float sq) { return artanh_c(sq * x) / sq; }

// Block reduction over 256 threads (4 waves).
template <int N>
__device__ __forceinline__ void block_reduce_sum(float* v, float* red) {
#pragma unroll
  for (int m = 1; m < 64; m <<= 1) {
#pragma unroll
    for (int i = 0; i < N; ++i) v[i] += __shfl_xor(v[i], m, 64);
  }
  int wid = threadIdx.x >> 6;
  int lane = threadIdx.x & 63;
  if (lane == 0) {
#pragma unroll
    for (int i = 0; i < N; ++i) red[wid * N + i] = v[i];
  }
  __syncthreads();
#pragma unroll
  for (int i = 0; i < N; ++i) v[i] = red[i] + red[N + i] + red[2 * N + i] + red[3 * N + i];
  __syncthreads();
}

// Build combined weight matrix, chunk-major: CW[j][c][k] = weight(k, col=j*8+c)
__global__ __launch_bounds__(256) void k_build_cw(const float* __restrict__ W_all,
                                                  const float* __restrict__ W_d,
                                                  float* __restrict__ CW) {
  int j = blockIdx.x;
  float* dst = CW + (size_t)j * 6144;
  for (int idx = threadIdx.x; idx < 6144; idx += 256) {
    int c = idx / 768;
    int k = idx - c * 768;
    int col = j * 8 + c;
    float v;
    if (col < 768) {
      v = W_d[col * 768 + k];
    } else {
      int jm = col - 768;
      int g = jm / 768;
      int j2 = jm - g * 768;
      v = W_all[j2 * 3072 + g * 768 + k];
    }
    dst[idx] = v;
  }
}

__global__ __launch_bounds__(256) void k_init_state(const float* __restrict__ h0,
                                                    const float* __restrict__ c0,
                                                    float* __restrict__ ccR, float* __restrict__ hR,
                                                    float* __restrict__ ccT, float* __restrict__ hT) {
  int r = blockIdx.x;
#pragma unroll
  for (int p = 0; p < 3; ++p) {
    int j = threadIdx.x + 256 * p;
    float cv = c0[r * 768 + j];
    float hv = h0[r * 768 + j];
    ccR[r * 768 + j] = cv;
    hR[r * 768 + j] = hv;
    ccT[j * 64 + r] = cv;
    hT[j * 64 + r] = hv;
  }
}

__global__ __launch_bounds__(256) void k_xnorm(const float* __restrict__ X,
                                               float* __restrict__ XN) {
  __shared__ float red[4];
  int r = blockIdx.x;
  float s = 0.f;
#pragma unroll
  for (int p = 0; p < 3; ++p) {
    float v = X[(size_t)r * 768 + threadIdx.x + 256 * p];
    s += v * v;
  }
#pragma unroll
  for (int m = 1; m < 64; m <<= 1) s += __shfl_xor(s, m, 64);
  if ((threadIdx.x & 63) == 0) red[threadIdx.x >> 6] = s;
  __syncthreads();
  if (threadIdx.x == 0) XN[r] = fmaxf(sqrtf(red[0] + red[1] + red[2] + red[3]), MINN);
}

// Split fp32 -> bf16 hi + bf16 lo (residual). Processes 4 elems/thread.
__global__ __launch_bounds__(256) void k_split(const float* __restrict__ src,
                                               __hip_bfloat16* __restrict__ hi,
                                               __hip_bfloat16* __restrict__ lo, int n4) {
  int i = blockIdx.x * 256 + threadIdx.x;
  if (i >= n4) return;
  f4 v = *(const f4*)(src + (size_t)i * 4);
#pragma unroll
  for (int j = 0; j < 4; ++j) {
    float x = (j == 0) ? v.x : (j == 1) ? v.y : (j == 2) ? v.z : v.w;
    __hip_bfloat16 h = __float2bfloat16(x);
    float r = x - __bfloat162float(h);
    hi[(size_t)i * 4 + j] = h;
    lo[(size_t)i * 4 + j] = __float2bfloat16(r);
  }
}

// MFMA U-path GEMM: OUT[i][m] = sum_k X[i][k]*U[m][k], fp32-accurate via
// hi/lo bf16 split (xh*uh + xl*uh + xh*ul). M=8192, N=3072, K=768.
// 64x64 tile/WG, 4 waves: wave w = rows [i0+16w, +16), 4 col-tiles of 16.
__global__ __launch_bounds__(256) void k_gemm_xu_mfma(
    const __hip_bfloat16* __restrict__ Xh, const __hip_bfloat16* __restrict__ Xl,
    const __hip_bfloat16* __restrict__ Uh, const __hip_bfloat16* __restrict__ Ul,
    __hip_bfloat16* __restrict__ OUT) {
  int tid = threadIdx.x;
  int wave = tid >> 6, lane = tid & 63;
  int r = lane & 15, kg = lane >> 4;  // fragment row/col & k-group
  int i0 = blockIdx.x * 64 + wave * 16;
  int m0 = blockIdx.y * 64;
  const __hip_bfloat16* xh = Xh + (size_t)(i0 + r) * 768 + kg * 8;
  const __hip_bfloat16* xl = Xl + (size_t)(i0 + r) * 768 + kg * 8;
  const __hip_bfloat16* uh = Uh + (size_t)(m0 + r) * 768 + kg * 8;
  const __hip_bfloat16* ul = Ul + (size_t)(m0 + r) * 768 + kg * 8;
  f32x4 acc0 = {0.f, 0.f, 0.f, 0.f};
  f32x4 acc1 = acc0, acc2 = acc0, acc3 = acc0;
  for (int k0 = 0; k0 < 768; k0 += 32) {
    bf16x8 ah = *(const bf16x8*)(xh + k0);
    bf16x8 al = *(const bf16x8*)(xl + k0);
    bf16x8 b0h = *(const bf16x8*)(uh + k0);
    bf16x8 b0l = *(const bf16x8*)(ul + k0);
    bf16x8 b1h = *(const bf16x8*)(uh + 12288 + k0);
    bf16x8 b1l = *(const bf16x8*)(ul + 12288 + k0);
    bf16x8 b2h = *(const bf16x8*)(uh + 24576 + k0);
    bf16x8 b2l = *(const bf16x8*)(ul + 24576 + k0);
    bf16x8 b3h = *(const bf16x8*)(uh + 36864 + k0);
    bf16x8 b3l = *(const bf16x8*)(ul + 36864 + k0);
    acc0 = __builtin_amdgcn_mfma_f32_16x16x32_bf16(ah, b0h, acc0, 0, 0, 0);
    acc1 = __builtin_amdgcn_mfma_f32_16x16x32_bf16(ah, b1h, acc1, 0, 0, 0);
    acc2 = __builtin_amdgcn_mfma_f32_16x16x32_bf16(ah, b2h, acc2, 0, 0, 0);
    acc3 = __builtin_amdgcn_mfma_f32_16x16x32_bf16(ah, b3h, acc3, 0, 0, 0);
    acc0 = __builtin_amdgcn_mfma_f32_16x16x32_bf16(al, b0h, acc0, 0, 0, 0);
    acc1 = __builtin_amdgcn_mfma_f32_16x16x32_bf16(al, b1h, acc1, 0, 0, 0);
    acc2 = __builtin_amdgcn_mfma_f32_16x16x32_bf16(al, b2h, acc2, 0, 0, 0);
    acc3 = __builtin_amdgcn_mfma_f32_16x16x32_bf16(al, b3h, acc3, 0, 0, 0);
    acc0 = __builtin_amdgcn_mfma_f32_16x16x32_bf16(ah, b0l, acc0, 0, 0, 0);
    acc1 = __builtin_amdgcn_mfma_f32_16x16x32_bf16(ah, b1l, acc1, 0, 0, 0);
    acc2 = __builtin_amdgcn_mfma_f32_16x16x32_bf16(ah, b2l, acc2, 0, 0, 0);
    acc3 = __builtin_amdgcn_mfma_f32_16x16x32_bf16(ah, b3l, acc3, 0, 0, 0);
  }
  // C/D layout: col = lane&15 (=r), row = kg*4 + j
#pragma unroll
  for (int j = 0; j < 4; ++j) {
    size_t row = (size_t)(i0 + kg * 4 + j) * 3072 + m0 + r;
    OUT[row] = __float2bfloat16(acc0[j]);
    OUT[row + 16] = __float2bfloat16(acc1[j]);
    OUT[row + 32] = __float2bfloat16(acc2[j]);
    OUT[row + 48] = __float2bfloat16(acc3[j]);
  }
}

// Per-step GEMM: GOUT[row][col] = sum_k state[k][row] * W[k][col].
// 480 WGs x 512 thr (2 WG/CU): 8 cols/WG, 4-way k-split, f4 dbuf pipeline.
__global__ __launch_bounds__(512) void k_step_gemm(const float* __restrict__ CW,
                                                   const float* __restrict__ ccT,
                                                   const float* __restrict__ hT,
                                                   float* __restrict__ GOUT) {
  __shared__ float Wl[8 * 772];  // 24.7 KB, [c][k] padded rows: b128-conflict-free
  __shared__ f4 Pacc[512];       // 8 KB partial combine
  int j = blockIdx.x;
  int tid = threadIdx.x;

  // Stage weights: 1536 f4 over 512 threads x 3.
  {
    const f4* s4 = (const f4*)(CW + (size_t)j * 6144);
#pragma unroll
    for (int it = 0; it < 3; ++it) {
      int f = tid + 512 * it;
      int cc = f / 192;        // col within chunk
      int kq = f - cc * 192;   // f4-group within col
      *(f4*)&Wl[cc * 772 + kq * 4] = s4[f];
    }
  }
  __syncthreads();

  const float* src = (j < 96) ? ccT : hT;
  int c = tid & 7;
  int rg = (tid >> 3) & 15;  // row-quad 0..15
  int kh = tid >> 7;         // k-quarter 0..3
  const float* sp = src + 4 * rg;   // + k*64 per hidden index k
  const int kb0 = kh * 192;
  const float* wrow = &Wl[c * 772];
  float a0 = 0.f, a1 = 0.f, a2 = 0.f, a3 = 0.f;
  f4 bufA[8], bufB[8];
#pragma unroll
  for (int i = 0; i < 8; ++i) bufA[i] = *(const f4*)(sp + (size_t)(kb0 + i) * 64);
  for (int kb = 0; kb < 24; kb += 2) {
#pragma unroll
    for (int i = 0; i < 8; ++i)
      bufB[i] = *(const f4*)(sp + (size_t)(kb0 + (kb + 1) * 8 + i) * 64);
#pragma unroll
    for (int iq = 0; iq < 2; ++iq) {
      f4 w = *(const f4*)(wrow + kb0 + kb * 8 + iq * 4);
#pragma unroll
      for (int jj = 0; jj < 4; ++jj) {
        float wj = (jj == 0) ? w.x : (jj == 1) ? w.y : (jj == 2) ? w.z : w.w;
        f4 s = bufA[iq * 4 + jj];
        a0 += s.x * wj; a1 += s.y * wj; a2 += s.z * wj; a3 += s.w * wj;
      }
    }
    if (kb + 2 < 24) {
#pragma unroll
      for (int i = 0; i < 8; ++i)
        bufA[i] = *(const f4*)(sp + (size_t)(kb0 + (kb + 2) * 8 + i) * 64);
    }
#pragma unroll
    for (int iq = 0; iq < 2; ++iq) {
      f4 w = *(const f4*)(wrow + kb0 + (kb + 1) * 8 + iq * 4);
#pragma unroll
      for (int jj = 0; jj < 4; ++jj) {
        float wj = (jj == 0) ? w.x : (jj == 1) ? w.y : (jj == 2) ? w.z : w.w;
        f4 s = bufB[iq * 4 + jj];
        a0 += s.x * wj; a1 += s.y * wj; a2 += s.z * wj; a3 += s.w * wj;
      }
    }
  }
  f4 pv;
  pv.x = a0; pv.y = a1; pv.z = a2; pv.w = a3;
  Pacc[tid] = pv;
  __syncthreads();
  if (tid < 128) {
    f4 p0 = Pacc[tid];
    f4 p1 = Pacc[tid + 128];
    f4 p2 = Pacc[tid + 256];
    f4 p3 = Pacc[tid + 384];
    int c2 = tid & 7;
    int rg2 = tid >> 3;
    int col = j * 8 + c2;
    GOUT[(4 * rg2 + 0) * NCOL + col] = p0.x + p1.x + p2.x + p3.x;
    GOUT[(4 * rg2 + 1) * NCOL + col] = p0.y + p1.y + p2.y + p3.y;
    GOUT[(4 * rg2 + 2) * NCOL + col] = p0.z + p1.z + p2.z + p3.z;
    GOUT[(4 * rg2 + 3) * NCOL + col] = p0.w + p1.w + p2.w + p3.w;
  }
}

// Per-step pointwise hyperbolic math; one WG per batch row (r1-proven).
__global__ __launch_bounds__(256) void k_step_pw(
    const float* __restrict__ GOUT, const __hip_bfloat16* __restrict__ UG,
    const float* __restrict__ XN, const float* __restrict__ TS,
    const float* __restrict__ kptr, float* __restrict__ ccR, float* __restrict__ hR,
    float* __restrict__ ccT, float* __restrict__ hT, float* __restrict__ out, int t) {
  __shared__ float red[64];
  int r = blockIdx.x;
  int tid = threadIdx.x;
  float kk = kptr[0];
  float sq = sqrtf(-kk);
  const float* grow = GOUT + r * NCOL;
  int i = r * SS + t;
  const __hip_bfloat16* urow = UG + (size_t)i * 3072;

  float cc[3], h[3], mv[3], gh[4][3], mx[4][3];
#pragma unroll
  for (int p = 0; p < 3; ++p) {
    int j = tid + 256 * p;
    cc[p] = ccR[r * 768 + j];
    h[p] = hR[r * 768 + j];
    mv[p] = grow[j];
#pragma unroll
    for (int g = 0; g < 4; ++g) {
      gh[g][p] = grow[768 + g * 768 + j];
      mx[g][p] = __bfloat162float(urow[g * 768 + j]);
    }
  }

  float sv[15];
#pragma unroll
  for (int q = 0; q < 15; ++q) sv[q] = 0.f;
#pragma unroll
  for (int p = 0; p < 3; ++p) {
    sv[0] += cc[p] * cc[p];
    sv[1] += h[p] * h[p];
    sv[2] += mv[p] * mv[p];
#pragma unroll
    for (int g = 0; g < 4; ++g) {
      sv[3 + g] += gh[g][p] * gh[g][p];
      sv[7 + g] += gh[g][p] * mx[g][p];
      sv[11 + g] += mx[g][p] * mx[g][p];
    }
  }
  block_reduce_sum<15>(sv, red);
  float c2 = sv[0], h2 = sv[1], mvn2 = sv[2];
  float xn_c = fmaxf(sqrtf(c2), MINN);
  float xn_h = fmaxf(sqrtf(h2), MINN);
  float mxn_d = fmaxf(sqrtf(mvn2), MINN);

  float r_d = (mxn_d / xn_c) * artan_k_(xn_c, sq);
  float twd = tan_k_(r_d, sq);
  float wdsc = twd / mxn_d;
  float yn_d = fmaxf(fabsf(twd), MINN);
  float lsc = (artan_k_(yn_d, sq) / yn_d) * wdsc;
  float th[3];
#pragma unroll
  for (int p = 0; p < 3; ++p) th[p] = tanhf(lsc * mv[p]);

  float uxn = XN[i];
  float ak_h = artan_k_(xn_h, sq);
  float ak_u = artan_k_(uxn, sq);
  float cAg[4], cBg[4], pscg[4];
#pragma unroll
  for (int g = 0; g < 4; ++g) {
    float ghn = fmaxf(sqrtf(sv[3 + g]), MINN);
    float tg = tan_k_((ghn / xn_h) * ak_h, sq);
    float wsc = tg / ghn;
    float w2 = tg * tg;
    float umxn = fmaxf(sqrtf(sv[11 + g]), MINN);
    float us = tan_k_((umxn / uxn) * ak_u, sq) / umxn;
    float u2 = us * us * sv[11 + g];
    float xy = wsc * us * sv[7 + g];
    float den = fmaxf(1.f - 2.f * kk * xy + kk * kk * w2 * u2, MINN);
    float a = (1.f - 2.f * kk * xy - kk * u2) / den;
    float b = (1.f + kk * w2) / den;
    float y2s = fmaxf(a * a * w2 + 2.f * a * b * xy + b * b * u2, 0.f);
    float yn = fmaxf(sqrtf(y2s), MINN);
    pscg[g] = artan_k_(yn, sq) / yn;
    cAg[g] = a * wsc;
    cBg[g] = b * us;
  }
  float gate[4][3];
#pragma unroll
  for (int g = 0; g < 4; ++g)
#pragma unroll
    for (int p = 0; p < 3; ++p)
      gate[g][p] = 1.f / (1.f + expf(-pscg[g] * (cAg[g] * gh[g][p] + cBg[g] * mx[g][p])));

  float s2v[2] = {0.f, 0.f};
#pragma unroll
  for (int p = 0; p < 3; ++p) {
    s2v[0] += th[p] * th[p];
    s2v[1] += th[p] * cc[p];
  }
  block_reduce_sum<2>(s2v, red);
  float un = fmaxf(sqrtf(s2v[0]), MINN);
  float esc = tan_k_(un, sq) / un;
  float cs1[3];
#pragma unroll
  for (int p = 0; p < 3; ++p) cs1[p] = esc * th[p];
  float d1 = esc * s2v[1];
  float s1sq = esc * esc * s2v[0];

  float tv = TS[r * SS + t];
  float xnt = fmaxf(sqrtf(768.f * tv * tv), MINN);
  float wxn_t = fmaxf(fabsf(tv) * sqrtf(s1sq), MINN);
  float s2s = tan_k_((wxn_t / xnt) * artan_k_(xnt, sq), sq) / wxn_t * tv;
  float s2sq = s2s * s2s * s1sq;

  float den_l = fmaxf(1.f + 2.f * kk * d1 + kk * kk * s1sq * c2, MINN);
  float al = (1.f + 2.f * kk * d1 - kk * c2) / den_l;
  float bl = (1.f + kk * s1sq) / den_l;
  float pcl = -al, qcl = bl;

  float xy2 = s2s * (pcl * s1sq + qcl * d1);
  float x2b = fmaxf(pcl * pcl * s1sq + 2.f * pcl * qcl * d1 + qcl * qcl * c2, 0.f);
  float y2b = s2sq;
  float den2 = fmaxf(1.f - 2.f * kk * xy2 + kk * kk * x2b * y2b, MINN);
  float a2 = (1.f - 2.f * kk * xy2 - kk * y2b) / den2;
  float b2 = (1.f + kk * x2b) / den2;
  float g1c = a2 * pcl + b2 * s2s;
  float g2c = a2 * qcl;
  float cadj[3];
#pragma unroll
  for (int p = 0; p < 3; ++p) cadj[p] = g1c * cs1[p] + g2c * cc[p];
  float adjsq = fmaxf(g1c * g1c * s1sq + 2.f * g1c * g2c * d1 + g2c * g2c * c2, 0.f);

  float wxi[3], wxf[3];
#pragma unroll
  for (int p = 0; p < 3; ++p) {
    wxi[p] = gate[1][p] * gate[3][p];
    wxf[p] = gate[0][p] * cadj[p];
  }
  float s3v[4] = {0.f, 0.f, 0.f, 0.f};
#pragma unroll
  for (int p = 0; p < 3; ++p) {
    s3v[0] += gate[3][p] * gate[3][p];
    s3v[1] += wxi[p] * wxi[p];
    s3v[2] += wxf[p] * wxf[p];
    s3v[3] += wxi[p] * wxf[p];
  }
  block_reduce_sum<4>(s3v, red);
  float xnct = fmaxf(sqrtf(s3v[0]), MINN);
  float wxni = fmaxf(sqrtf(s3v[1]), MINN);
  float psi = tan_k_((wxni / xnct) * artan_k_(xnct, sq), sq) / wxni;
  float pi2 = psi * psi * s3v[1];
  float xnadj = fmaxf(sqrtf(adjsq), MINN);
  float wxnf = fmaxf(sqrtf(s3v[2]), MINN);
  float psf = tan_k_((wxnf / xnadj) * artan_k_(xnadj, sq), sq) / wxnf;
  float pf2 = psf * psf * s3v[2];
  float xyp = psi * psf * s3v[3];
  float den3 = fmaxf(1.f - 2.f * kk * xyp + kk * kk * pi2 * pf2, MINN);
  float a3 = (1.f - 2.f * kk * xyp - kk * pf2) / den3;
  float b3 = (1.f + kk * pi2) / den3;
  float nc[3], tc[3];
#pragma unroll
  for (int p = 0; p < 3; ++p) {
    nc[p] = a3 * psi * wxi[p] + b3 * psf * wxf[p];
    tc[p] = tanhf(nc[p]);
  }
  float s4v[1] = {0.f};
#pragma unroll
  for (int p = 0; p < 3; ++p) s4v[0] += tc[p] * tc[p];
  block_reduce_sum<1>(s4v, red);
  float unh = fmaxf(sqrtf(s4v[0]), MINN);
  float ehs = tan_k_(unh, sq) / unh;
  float Esq = ehs * ehs * s4v[0];
  float En = fmaxf(sqrtf(Esq), MINN);
  float wxo[3];
#pragma unroll
  for (int p = 0; p < 3; ++p) wxo[p] = gate[2][p] * (ehs * tc[p]);
  float s5v[1] = {0.f};
#pragma unroll
  for (int p = 0; p < 3; ++p) s5v[0] += wxo[p] * wxo[p];
  block_reduce_sum<1>(s5v, red);
  float wxno = fmaxf(sqrtf(s5v[0]), MINN);
  float pso = tan_k_((wxno / En) * artan_k_(En, sq), sq) / wxno;

  size_t BSHc = (size_t)BB * SS * 768;
#pragma unroll
  for (int p = 0; p < 3; ++p) {
    int j = tid + 256 * p;
    out[((size_t)r * SS + t) * 768 + j] = gate[2][p];  // output = o gate
    float ncv = nc[p];
    float nhv = pso * wxo[p];
    ccR[r * 768 + j] = ncv;
    ccT[j * 64 + r] = ncv;
    hR[r * 768 + j] = nhv;
    hT[j * 64 + r] = nhv;
    if (t == SS - 1) {
      out[BSHc + (size_t)r * 768 + j] = nhv;                    // h_last
      out[BSHc + (size_t)BB * 768 + (size_t)r * 768 + j] = ncv; // c_last
    }
  }
}

extern "C" void kernel_launch(void* const* d_in, const int* in_sizes, int n_in,
                              void* d_out, int out_size, void* d_ws, size_t ws_size,
                              hipStream_t stream) {
  const float* inputs = (const float*)d_in[0];
  const float* ts = (const float*)d_in[1];
  const float* h0 = (const float*)d_in[2];
  const float* c0 = (const float*)d_in[3];
  const float* W_all = (const float*)d_in[4];
  const float* U_all = (const float*)d_in[5];
  const float* W_d = (const float*)d_in[6];
  const float* kptr = (const float*)d_in[7];
  float* ws = (float*)d_ws;
  float* out = (float*)d_out;

  size_t oCW = 0;
  size_t oCCT = oCW + (size_t)NCHUNK * 6144;  // 2,949,120 floats
  size_t oHT = oCCT + 49152;
  size_t oCCR = oHT + 49152;
  size_t oHR = oCCR + 49152;
  size_t oGOUT = oHR + 49152;
  size_t oXN = oGOUT + (size_t)BB * NCOL;
  size_t oUG = oXN + 8192;                    // UG: 25,165,824 bf16 = 12,582,912 floats
  size_t oXH = oUG + 12582912;                // Xh: 6,291,456 bf16 = 3,145,728 floats
  size_t oXL = oXH + 3145728;
  size_t oUH = oXL + 3145728;                 // Uh: 2,359,296 bf16 = 1,179,648 floats
  size_t oUL = oUH + 1179648;

  float* cw = ws + oCW;
  float* cct = ws + oCCT;
  float* ht = ws + oHT;
  float* ccr = ws + oCCR;
  float* hr = ws + oHR;
  float* gout = ws + oGOUT;
  float* xn = ws + oXN;
  __hip_bfloat16* ug = (__hip_bfloat16*)(ws + oUG);
  __hip_bfloat16* xhh = (__hip_bfloat16*)(ws + oXH);
  __hip_bfloat16* xll = (__hip_bfloat16*)(ws + oXL);
  __hip_bfloat16* uhh = (__hip_bfloat16*)(ws + oUH);
  __hip_bfloat16* ull = (__hip_bfloat16*)(ws + oUL);

  k_build_cw<<<NCHUNK, 256, 0, stream>>>(W_all, W_d, cw);
  k_init_state<<<BB, 256, 0, stream>>>(h0, c0, ccr, hr, cct, ht);
  k_split<<<(6291456 / 4 + 255) / 256, 256, 0, stream>>>(inputs, xhh, xll, 6291456 / 4);
  k_split<<<(2359296 / 4 + 255) / 256, 256, 0, stream>>>(U_all, uhh, ull, 2359296 / 4);
  k_gemm_xu_mfma<<<dim3(128, 48), 256, 0, stream>>>(xhh, xll, uhh, ull, ug);
  k_xnorm<<<BB * SS, 256, 0, stream>>>(inputs, xn);

  for (int t = 0; t < SS; ++t) {
    k_step_gemm<<<NCHUNK, 512, 0, stream>>>(cw, cct, ht, gout);
    k_step_pw<<<BB, 256, 0, stream>>>(gout, ug, xn, ts, kptr, ccr, hr, cct, ht, out, t);
  }
}

// Round 9
// 4203.075 us; speedup vs baseline: 8.0067x; 1.3207x over previous
//
#include <hip/hip_runtime.h>
#include <hip/hip_bf16.h>
#include <math.h>

#define MINN 1e-7f

// Problem dims (fixed by setup_inputs)
#define BB 64
#define SS 128
#define NCOL 3840            // 768 (W_d) + 4*768 (gates)

typedef float f4 __attribute__((ext_vector_type(4)));
typedef short bf16x8 __attribute__((ext_vector_type(8)));
typedef float f32x4 __attribute__((ext_vector_type(4)));

__device__ __forceinline__ float artanh_c(float x) {
  x = fminf(fmaxf(x, -1.0f + 1e-6f), 1.0f - 1e-6f);
  return atanhf(x);
}
__device__ __forceinline__ float tan_k_(float x, float sq) { return tanhf(sq * x) / sq; }
__device__ __forceinline__ float artan_k_(float x, float sq) { return artanh_c(sq * x) / sq; }

// Block reduction over 256 threads (4 waves).
template <int N>
__device__ __forceinline__ void block_reduce_sum(float* v, float* red) {
#pragma unroll
  for (int m = 1; m < 64; m <<= 1) {
#pragma unroll
    for (int i = 0; i < N; ++i) v[i] += __shfl_xor(v[i], m, 64);
  }
  int wid = threadIdx.x >> 6;
  int lane = threadIdx.x & 63;
  if (lane == 0) {
#pragma unroll
    for (int i = 0; i < N; ++i) red[wid * N + i] = v[i];
  }
  __syncthreads();
#pragma unroll
  for (int i = 0; i < N; ++i) v[i] = red[i] + red[N + i] + red[2 * N + i] + red[3 * N + i];
  __syncthreads();
}

// Build combined weight matrix as bf16 hi/lo, [col][k] (k-contiguous = B-fragment ready).
__global__ __launch_bounds__(256) void k_build_cw(const float* __restrict__ W_all,
                                                  const float* __restrict__ W_d,
                                                  __hip_bfloat16* __restrict__ CWh,
                                                  __hip_bfloat16* __restrict__ CWl) {
  int col = blockIdx.x;  // 0..3839
#pragma unroll
  for (int p = 0; p < 3; ++p) {
    int k = threadIdx.x + 256 * p;
    float v;
    if (col < 768) {
      v = W_d[col * 768 + k];
    } else {
      int jm = col - 768;
      int g = jm / 768;
      int j2 = jm - g * 768;
      v = W_all[j2 * 3072 + g * 768 + k];
    }
    __hip_bfloat16 h = __float2bfloat16(v);
    CWh[(size_t)col * 768 + k] = h;
    CWl[(size_t)col * 768 + k] = __float2bfloat16(v - __bfloat162float(h));
  }
}

// Init: fp32 row-major state + bf16 hi/lo row-major copies (A-fragment ready).
__global__ __launch_bounds__(256) void k_init_state(
    const float* __restrict__ h0, const float* __restrict__ c0,
    float* __restrict__ ccR, float* __restrict__ hR,
    __hip_bfloat16* __restrict__ CH, __hip_bfloat16* __restrict__ CL,
    __hip_bfloat16* __restrict__ HH, __hip_bfloat16* __restrict__ HL) {
  int r = blockIdx.x;
#pragma unroll
  for (int p = 0; p < 3; ++p) {
    int j = threadIdx.x + 256 * p;
    float cv = c0[r * 768 + j];
    float hv = h0[r * 768 + j];
    ccR[r * 768 + j] = cv;
    hR[r * 768 + j] = hv;
    __hip_bfloat16 ch = __float2bfloat16(cv);
    CH[r * 768 + j] = ch;
    CL[r * 768 + j] = __float2bfloat16(cv - __bfloat162float(ch));
    __hip_bfloat16 hh = __float2bfloat16(hv);
    HH[r * 768 + j] = hh;
    HL[r * 768 + j] = __float2bfloat16(hv - __bfloat162float(hh));
  }
}

__global__ __launch_bounds__(256) void k_xnorm(const float* __restrict__ X,
                                               float* __restrict__ XN) {
  __shared__ float red[4];
  int r = blockIdx.x;
  float s = 0.f;
#pragma unroll
  for (int p = 0; p < 3; ++p) {
    float v = X[(size_t)r * 768 + threadIdx.x + 256 * p];
    s += v * v;
  }
#pragma unroll
  for (int m = 1; m < 64; m <<= 1) s += __shfl_xor(s, m, 64);
  if ((threadIdx.x & 63) == 0) red[threadIdx.x >> 6] = s;
  __syncthreads();
  if (threadIdx.x == 0) XN[r] = fmaxf(sqrtf(red[0] + red[1] + red[2] + red[3]), MINN);
}

// Split fp32 -> bf16 hi + bf16 lo (residual). Processes 4 elems/thread.
__global__ __launch_bounds__(256) void k_split(const float* __restrict__ src,
                                               __hip_bfloat16* __restrict__ hi,
                                               __hip_bfloat16* __restrict__ lo, int n4) {
  int i = blockIdx.x * 256 + threadIdx.x;
  if (i >= n4) return;
  f4 v = *(const f4*)(src + (size_t)i * 4);
#pragma unroll
  for (int j = 0; j < 4; ++j) {
    float x = (j == 0) ? v.x : (j == 1) ? v.y : (j == 2) ? v.z : v.w;
    __hip_bfloat16 h = __float2bfloat16(x);
    float r = x - __bfloat162float(h);
    hi[(size_t)i * 4 + j] = h;
    lo[(size_t)i * 4 + j] = __float2bfloat16(r);
  }
}

// MFMA U-path GEMM (r8-proven): OUT[i][m] = sum_k X[i][k]*U[m][k].
__global__ __launch_bounds__(256) void k_gemm_xu_mfma(
    const __hip_bfloat16* __restrict__ Xh, const __hip_bfloat16* __restrict__ Xl,
    const __hip_bfloat16* __restrict__ Uh, const __hip_bfloat16* __restrict__ Ul,
    __hip_bfloat16* __restrict__ OUT) {
  int tid = threadIdx.x;
  int wave = tid >> 6, lane = tid & 63;
  int r = lane & 15, kg = lane >> 4;
  int i0 = blockIdx.x * 64 + wave * 16;
  int m0 = blockIdx.y * 64;
  const __hip_bfloat16* xh = Xh + (size_t)(i0 + r) * 768 + kg * 8;
  const __hip_bfloat16* xl = Xl + (size_t)(i0 + r) * 768 + kg * 8;
  const __hip_bfloat16* uh = Uh + (size_t)(m0 + r) * 768 + kg * 8;
  const __hip_bfloat16* ul = Ul + (size_t)(m0 + r) * 768 + kg * 8;
  f32x4 acc0 = {0.f, 0.f, 0.f, 0.f};
  f32x4 acc1 = acc0, acc2 = acc0, acc3 = acc0;
  for (int k0 = 0; k0 < 768; k0 += 32) {
    bf16x8 ah = *(const bf16x8*)(xh + k0);
    bf16x8 al = *(const bf16x8*)(xl + k0);
    bf16x8 b0h = *(const bf16x8*)(uh + k0);
    bf16x8 b0l = *(const bf16x8*)(ul + k0);
    bf16x8 b1h = *(const bf16x8*)(uh + 12288 + k0);
    bf16x8 b1l = *(const bf16x8*)(ul + 12288 + k0);
    bf16x8 b2h = *(const bf16x8*)(uh + 24576 + k0);
    bf16x8 b2l = *(const bf16x8*)(ul + 24576 + k0);
    bf16x8 b3h = *(const bf16x8*)(uh + 36864 + k0);
    bf16x8 b3l = *(const bf16x8*)(ul + 36864 + k0);
    acc0 = __builtin_amdgcn_mfma_f32_16x16x32_bf16(ah, b0h, acc0, 0, 0, 0);
    acc1 = __builtin_amdgcn_mfma_f32_16x16x32_bf16(ah, b1h, acc1, 0, 0, 0);
    acc2 = __builtin_amdgcn_mfma_f32_16x16x32_bf16(ah, b2h, acc2, 0, 0, 0);
    acc3 = __builtin_amdgcn_mfma_f32_16x16x32_bf16(ah, b3h, acc3, 0, 0, 0);
    acc0 = __builtin_amdgcn_mfma_f32_16x16x32_bf16(al, b0h, acc0, 0, 0, 0);
    acc1 = __builtin_amdgcn_mfma_f32_16x16x32_bf16(al, b1h, acc1, 0, 0, 0);
    acc2 = __builtin_amdgcn_mfma_f32_16x16x32_bf16(al, b2h, acc2, 0, 0, 0);
    acc3 = __builtin_amdgcn_mfma_f32_16x16x32_bf16(al, b3h, acc3, 0, 0, 0);
    acc0 = __builtin_amdgcn_mfma_f32_16x16x32_bf16(ah, b0l, acc0, 0, 0, 0);
    acc1 = __builtin_amdgcn_mfma_f32_16x16x32_bf16(ah, b1l, acc1, 0, 0, 0);
    acc2 = __builtin_amdgcn_mfma_f32_16x16x32_bf16(ah, b2l, acc2, 0, 0, 0);
    acc3 = __builtin_amdgcn_mfma_f32_16x16x32_bf16(ah, b3l, acc3, 0, 0, 0);
  }
#pragma unroll
  for (int j = 0; j < 4; ++j) {
    size_t row = (size_t)(i0 + kg * 4 + j) * 3072 + m0 + r;
    OUT[row] = __float2bfloat16(acc0[j]);
    OUT[row + 16] = __float2bfloat16(acc1[j]);
    OUT[row + 32] = __float2bfloat16(acc2[j]);
    OUT[row + 48] = __float2bfloat16(acc3[j]);
  }
}

// Per-step recurrent GEMM via MFMA hi/lo: GOUT[i][m] = sum_k state[i][k]*CW[m][k].
// 240 WGs (one 16-col tile each) x 4 waves (16-row tiles covering all 64 rows).
__global__ __launch_bounds__(256) void k_step_gemm_mfma(
    const __hip_bfloat16* __restrict__ CWh, const __hip_bfloat16* __restrict__ CWl,
    const __hip_bfloat16* __restrict__ CH, const __hip_bfloat16* __restrict__ CL,
    const __hip_bfloat16* __restrict__ HH, const __hip_bfloat16* __restrict__ HL,
    float* __restrict__ GOUT) {
  int j = blockIdx.x;  // col-tile 0..239
  int wave = threadIdx.x >> 6, lane = threadIdx.x & 63;
  int r = lane & 15, kg = lane >> 4;
  int i0 = wave * 16;
  int m0 = j * 16;
  const __hip_bfloat16* sh = (j < 48 ? CH : HH) + (size_t)(i0 + r) * 768 + kg * 8;
  const __hip_bfloat16* sl = (j < 48 ? CL : HL) + (size_t)(i0 + r) * 768 + kg * 8;
  const __hip_bfloat16* wh = CWh + (size_t)(m0 + r) * 768 + kg * 8;
  const __hip_bfloat16* wl = CWl + (size_t)(m0 + r) * 768 + kg * 8;
  f32x4 acc = {0.f, 0.f, 0.f, 0.f};
#pragma unroll 4
  for (int k0 = 0; k0 < 768; k0 += 32) {
    bf16x8 ah = *(const bf16x8*)(sh + k0);
    bf16x8 al = *(const bf16x8*)(sl + k0);
    bf16x8 bh = *(const bf16x8*)(wh + k0);
    bf16x8 bl = *(const bf16x8*)(wl + k0);
    acc = __builtin_amdgcn_mfma_f32_16x16x32_bf16(ah, bh, acc, 0, 0, 0);
    acc = __builtin_amdgcn_mfma_f32_16x16x32_bf16(al, bh, acc, 0, 0, 0);
    acc = __builtin_amdgcn_mfma_f32_16x16x32_bf16(ah, bl, acc, 0, 0, 0);
  }
  // C/D: m = m0 + (lane&15), i = i0 + kg*4 + jj
#pragma unroll
  for (int jj = 0; jj < 4; ++jj)
    GOUT[(size_t)(i0 + kg * 4 + jj) * NCOL + m0 + r] = acc[jj];
}

// Per-step pointwise hyperbolic math; one WG per batch row.
__global__ __launch_bounds__(256) void k_step_pw(
    const float* __restrict__ GOUT, const __hip_bfloat16* __restrict__ UG,
    const float* __restrict__ XN, const float* __restrict__ TS,
    const float* __restrict__ kptr, float* __restrict__ ccR, float* __restrict__ hR,
    __hip_bfloat16* __restrict__ CH, __hip_bfloat16* __restrict__ CL,
    __hip_bfloat16* __restrict__ HH, __hip_bfloat16* __restrict__ HL,
    float* __restrict__ out, int t) {
  __shared__ float red[64];
  int r = blockIdx.x;
  int tid = threadIdx.x;
  float kk = kptr[0];
  float sq = sqrtf(-kk);
  const float* grow = GOUT + r * NCOL;
  int i = r * SS + t;
  const __hip_bfloat16* urow = UG + (size_t)i * 3072;

  float cc[3], h[3], mv[3], gh[4][3], mx[4][3];
#pragma unroll
  for (int p = 0; p < 3; ++p) {
    int j = tid + 256 * p;
    cc[p] = ccR[r * 768 + j];
    h[p] = hR[r * 768 + j];
    mv[p] = grow[j];
#pragma unroll
    for (int g = 0; g < 4; ++g) {
      gh[g][p] = grow[768 + g * 768 + j];
      mx[g][p] = __bfloat162float(urow[g * 768 + j]);
    }
  }

  float sv[15];
#pragma unroll
  for (int q = 0; q < 15; ++q) sv[q] = 0.f;
#pragma unroll
  for (int p = 0; p < 3; ++p) {
    sv[0] += cc[p] * cc[p];
    sv[1] += h[p] * h[p];
    sv[2] += mv[p] * mv[p];
#pragma unroll
    for (int g = 0; g < 4; ++g) {
      sv[3 + g] += gh[g][p] * gh[g][p];
      sv[7 + g] += gh[g][p] * mx[g][p];
      sv[11 + g] += mx[g][p] * mx[g][p];
    }
  }
  block_reduce_sum<15>(sv, red);
  float c2 = sv[0], h2 = sv[1], mvn2 = sv[2];
  float xn_c = fmaxf(sqrtf(c2), MINN);
  float xn_h = fmaxf(sqrtf(h2), MINN);
  float mxn_d = fmaxf(sqrtf(mvn2), MINN);

  float r_d = (mxn_d / xn_c) * artan_k_(xn_c, sq);
  float twd = tan_k_(r_d, sq);
  float wdsc = twd / mxn_d;
  float yn_d = fmaxf(fabsf(twd), MINN);
  float lsc = (artan_k_(yn_d, sq) / yn_d) * wdsc;
  float th[3];
#pragma unroll
  for (int p = 0; p < 3; ++p) th[p] = tanhf(lsc * mv[p]);

  float uxn = XN[i];
  float ak_h = artan_k_(xn_h, sq);
  float ak_u = artan_k_(uxn, sq);
  float cAg[4], cBg[4], pscg[4];
#pragma unroll
  for (int g = 0; g < 4; ++g) {
    float ghn = fmaxf(sqrtf(sv[3 + g]), MINN);
    float tg = tan_k_((ghn / xn_h) * ak_h, sq);
    float wsc = tg / ghn;
    float w2 = tg * tg;
    float umxn = fmaxf(sqrtf(sv[11 + g]), MINN);
    float us = tan_k_((umxn / uxn) * ak_u, sq) / umxn;
    float u2 = us * us * sv[11 + g];
    float xy = wsc * us * sv[7 + g];
    float den = fmaxf(1.f - 2.f * kk * xy + kk * kk * w2 * u2, MINN);
    float a = (1.f - 2.f * kk * xy - kk * u2) / den;
    float b = (1.f + kk * w2) / den;
    float y2s = fmaxf(a * a * w2 + 2.f * a * b * xy + b * b * u2, 0.f);
    float yn = fmaxf(sqrtf(y2s), MINN);
    pscg[g] = artan_k_(yn, sq) / yn;
    cAg[g] = a * wsc;
    cBg[g] = b * us;
  }
  float gate[4][3];
#pragma unroll
  for (int g = 0; g < 4; ++g)
#pragma unroll
    for (int p = 0; p < 3; ++p)
      gate[g][p] = 1.f / (1.f + expf(-pscg[g] * (cAg[g] * gh[g][p] + cBg[g] * mx[g][p])));

  float s2v[2] = {0.f, 0.f};
#pragma unroll
  for (int p = 0; p < 3; ++p) {
    s2v[0] += th[p] * th[p];
    s2v[1] += th[p] * cc[p];
  }
  block_reduce_sum<2>(s2v, red);
  float un = fmaxf(sqrtf(s2v[0]), MINN);
  float esc = tan_k_(un, sq) / un;
  float cs1[3];
#pragma unroll
  for (int p = 0; p < 3; ++p) cs1[p] = esc * th[p];
  float d1 = esc * s2v[1];
  float s1sq = esc * esc * s2v[0];

  float tv = TS[r * SS + t];
  float xnt = fmaxf(sqrtf(768.f * tv * tv), MINN);
  float wxn_t = fmaxf(fabsf(tv) * sqrtf(s1sq), MINN);
  float s2s = tan_k_((wxn_t / xnt) * artan_k_(xnt, sq), sq) / wxn_t * tv;
  float s2sq = s2s * s2s * s1sq;

  float den_l = fmaxf(1.f + 2.f * kk * d1 + kk * kk * s1sq * c2, MINN);
  float al = (1.f + 2.f * kk * d1 - kk * c2) / den_l;
  float bl = (1.f + kk * s1sq) / den_l;
  float pcl = -al, qcl = bl;

  float xy2 = s2s * (pcl * s1sq + qcl * d1);
  float x2b = fmaxf(pcl * pcl * s1sq + 2.f * pcl * qcl * d1 + qcl * qcl * c2, 0.f);
  float y2b = s2sq;
  float den2 = fmaxf(1.f - 2.f * kk * xy2 + kk * kk * x2b * y2b, MINN);
  float a2 = (1.f - 2.f * kk * xy2 - kk * y2b) / den2;
  float b2 = (1.f + kk * x2b) / den2;
  float g1c = a2 * pcl + b2 * s2s;
  float g2c = a2 * qcl;
  float cadj[3];
#pragma unroll
  for (int p = 0; p < 3; ++p) cadj[p] = g1c * cs1[p] + g2c * cc[p];
  float adjsq = fmaxf(g1c * g1c * s1sq + 2.f * g1c * g2c * d1 + g2c * g2c * c2, 0.f);

  float wxi[3], wxf[3];
#pragma unroll
  for (int p = 0; p < 3; ++p) {
    wxi[p] = gate[1][p] * gate[3][p];
    wxf[p] = gate[0][p] * cadj[p];
  }
  float s3v[4] = {0.f, 0.f, 0.f, 0.f};
#pragma unroll
  for (int p = 0; p < 3; ++p) {
    s3v[0] += gate[3][p] * gate[3][p];
    s3v[1] += wxi[p] * wxi[p];
    s3v[2] += wxf[p] * wxf[p];
    s3v[3] += wxi[p] * wxf[p];
  }
  block_reduce_sum<4>(s3v, red);
  float xnct = fmaxf(sqrtf(s3v[0]), MINN);
  float wxni = fmaxf(sqrtf(s3v[1]), MINN);
  float psi = tan_k_((wxni / xnct) * artan_k_(xnct, sq), sq) / wxni;
  float pi2 = psi * psi * s3v[1];
  float xnadj = fmaxf(sqrtf(adjsq), MINN);
  float wxnf = fmaxf(sqrtf(s3v[2]), MINN);
  float psf = tan_k_((wxnf / xnadj) * artan_k_(xnadj, sq), sq) / wxnf;
  float pf2 = psf * psf * s3v[2];
  float xyp = psi * psf * s3v[3];
  float den3 = fmaxf(1.f - 2.f * kk * xyp + kk * kk * pi2 * pf2, MINN);
  float a3 = (1.f - 2.f * kk * xyp - kk * pf2) / den3;
  float b3 = (1.f + kk * pi2) / den3;
  float nc[3], tc[3];
#pragma unroll
  for (int p = 0; p < 3; ++p) {
    nc[p] = a3 * psi * wxi[p] + b3 * psf * wxf[p];
    tc[p] = tanhf(nc[p]);
  }
  float s4v[1] = {0.f};
#pragma unroll
  for (int p = 0; p < 3; ++p) s4v[0] += tc[p] * tc[p];
  block_reduce_sum<1>(s4v, red);
  float unh = fmaxf(sqrtf(s4v[0]), MINN);
  float ehs = tan_k_(unh, sq) / unh;
  float Esq = ehs * ehs * s4v[0];
  float En = fmaxf(sqrtf(Esq), MINN);
  float wxo[3];
#pragma unroll
  for (int p = 0; p < 3; ++p) wxo[p] = gate[2][p] * (ehs * tc[p]);
  float s5v[1] = {0.f};
#pragma unroll
  for (int p = 0; p < 3; ++p) s5v[0] += wxo[p] * wxo[p];
  block_reduce_sum<1>(s5v, red);
  float wxno = fmaxf(sqrtf(s5v[0]), MINN);
  float pso = tan_k_((wxno / En) * artan_k_(En, sq), sq) / wxno;

  size_t BSHc = (size_t)BB * SS * 768;
#pragma unroll
  for (int p = 0; p < 3; ++p) {
    int j = tid + 256 * p;
    out[((size_t)r * SS + t) * 768 + j] = gate[2][p];  // output = o gate
    float ncv = nc[p];
    float nhv = pso * wxo[p];
    ccR[r * 768 + j] = ncv;
    hR[r * 768 + j] = nhv;
    // bf16 hi/lo A-fragments for next step's MFMA GEMM
    __hip_bfloat16 chh = __float2bfloat16(ncv);
    CH[r * 768 + j] = chh;
    CL[r * 768 + j] = __float2bfloat16(ncv - __bfloat162float(chh));
    __hip_bfloat16 hhh = __float2bfloat16(nhv);
    HH[r * 768 + j] = hhh;
    HL[r * 768 + j] = __float2bfloat16(nhv - __bfloat162float(hhh));
    if (t == SS - 1) {
      out[BSHc + (size_t)r * 768 + j] = nhv;                    // h_last
      out[BSHc + (size_t)BB * 768 + (size_t)r * 768 + j] = ncv; // c_last
    }
  }
}

extern "C" void kernel_launch(void* const* d_in, const int* in_sizes, int n_in,
                              void* d_out, int out_size, void* d_ws, size_t ws_size,
                              hipStream_t stream) {
  const float* inputs = (const float*)d_in[0];
  const float* ts = (const float*)d_in[1];
  const float* h0 = (const float*)d_in[2];
  const float* c0 = (const float*)d_in[3];
  const float* W_all = (const float*)d_in[4];
  const float* U_all = (const float*)d_in[5];
  const float* W_d = (const float*)d_in[6];
  const float* kptr = (const float*)d_in[7];
  float* ws = (float*)d_ws;
  float* out = (float*)d_out;

  // all offsets in float units
  size_t oCWH = 0;                     // 3840*768 bf16 = 1,474,560 fl
  size_t oCWL = oCWH + 1474560;
  size_t oCCR = oCWL + 1474560;        // fp32 state 49,152 fl each
  size_t oHR = oCCR + 49152;
  size_t oCH = oHR + 49152;            // bf16 state 24,576 fl each
  size_t oCL = oCH + 24576;
  size_t oHH = oCL + 24576;
  size_t oHL = oHH + 24576;
  size_t oGOUT = oHL + 24576;          // 245,760 fl
  size_t oXN = oGOUT + (size_t)BB * NCOL;
  size_t oUG = oXN + 8192;             // 12,582,912 fl
  size_t oXH = oUG + 12582912;         // 3,145,728 fl
  size_t oXL = oXH + 3145728;
  size_t oUH = oXL + 3145728;          // 1,179,648 fl
  size_t oUL = oUH + 1179648;

  __hip_bfloat16* cwh = (__hip_bfloat16*)(ws + oCWH);
  __hip_bfloat16* cwl = (__hip_bfloat16*)(ws + oCWL);
  float* ccr = ws + oCCR;
  float* hr = ws + oHR;
  __hip_bfloat16* ch = (__hip_bfloat16*)(ws + oCH);
  __hip_bfloat16* cl = (__hip_bfloat16*)(ws + oCL);
  __hip_bfloat16* hh = (__hip_bfloat16*)(ws + oHH);
  __hip_bfloat16* hl = (__hip_bfloat16*)(ws + oHL);
  float* gout = ws + oGOUT;
  float* xn = ws + oXN;
  __hip_bfloat16* ug = (__hip_bfloat16*)(ws + oUG);
  __hip_bfloat16* xhh = (__hip_bfloat16*)(ws + oXH);
  __hip_bfloat16* xll = (__hip_bfloat16*)(ws + oXL);
  __hip_bfloat16* uhh = (__hip_bfloat16*)(ws + oUH);
  __hip_bfloat16* ull = (__hip_bfloat16*)(ws + oUL);

  k_build_cw<<<NCOL, 256, 0, stream>>>(W_all, W_d, cwh, cwl);
  k_init_state<<<BB, 256, 0, stream>>>(h0, c0, ccr, hr, ch, cl, hh, hl);
  k_split<<<(6291456 / 4 + 255) / 256, 256, 0, stream>>>(inputs, xhh, xll, 6291456 / 4);
  k_split<<<(2359296 / 4 + 255) / 256, 256, 0, stream>>>(U_all, uhh, ull, 2359296 / 4);
  k_gemm_xu_mfma<<<dim3(128, 48), 256, 0, stream>>>(xhh, xll, uhh, ull, ug);
  k_xnorm<<<BB * SS, 256, 0, stream>>>(inputs, xn);

  for (int t = 0; t < SS; ++t) {
    k_step_gemm_mfma<<<240, 256, 0, stream>>>(cwh, cwl, ch, cl, hh, hl, gout);
    k_step_pw<<<BB, 256, 0, stream>>>(gout, ug, xn, ts, kptr, ccr, hr, ch, cl, hh, hl,
                                      out, t);
  }
}